// Round 2
// baseline (388.017 us; speedup 1.0000x reference)
//
#include <hip/hip_runtime.h>
#include <hip/hip_bf16.h>
#include <math.h>

#define NN 1024
#define LDIM 32
#define HDIM 64

// ---------------- workspace layout (float offsets) ----------------
#define WS_SELF   0                         // N*L  self_term [i][l]
#define WS_AA     (WS_SELF + NN*LDIM)       // N*H  a [i][h]        (uniform per i)
#define WS_BT     (WS_AA   + NN*HDIM)       // H*N  b transposed [h][j]
#define WS_HT     (WS_BT   + HDIM*NN)       // L*N  h transposed [l][j]
#define WS_CI     (WS_HT   + LDIM*NN)       // N*L  ci [i][l]       (uniform per i)
#define WS_CJT    (WS_CI   + NN*LDIM)       // L*N  cj transposed [l][j]
#define WS_PH     (WS_CJT  + LDIM*NN)       // N    phases
#define WS_AGG    (WS_PH   + NN)            // N    sigmoid(aggr)
#define WS_ISUM   (WS_AGG  + NN)            // N*L  fp32 accumulators (memset 0)
#define WS_WI2T   (WS_ISUM + NN*LDIM)       // H*H  Wi2 transposed [h][h']
#define WS_WI3T   (WS_WI2T + HDIM*HDIM)     // H*L  Wi3 transposed [h][l]
#define WS_BI2    (WS_WI3T + HDIM*LDIM)     // H
#define WS_BI3    (WS_BI2  + HDIM)          // L
#define WS_BC     (WS_BI3  + LDIM)          // L
#define WS_PHW    (WS_BC   + LDIM)          // L
#define WS_TOTAL  (WS_PHW  + LDIM)          // ~303k floats = 1.2 MB

__device__ __forceinline__ float fast_rcp(float x) { return __builtin_amdgcn_rcpf(x); }

__device__ __forceinline__ float fast_tanh(float x) {
    // tanh(x) = 1 - 2/(exp(2x)+1); saturates cleanly at +-inf
    float e = __expf(2.0f * x);
    return 1.0f - 2.0f * fast_rcp(e + 1.0f);
}
__device__ __forceinline__ float fast_sigmoid(float x) {
    return fast_rcp(1.0f + __expf(-x));
}

// ---------------- kernel 1: transpose weights into ws ----------------
__global__ __launch_bounds__(256) void conv_weights(
    const float* __restrict__ Wi2, const float* __restrict__ bi2,
    const float* __restrict__ Wi3, const float* __restrict__ bi3,
    const float* __restrict__ bcp, const float* __restrict__ phw,
    float* __restrict__ ws) {
    int t = blockIdx.x * 256 + threadIdx.x;
    if (t < HDIM * HDIM) {                 // Wi2T[h][h'] = Wi2[h'][h]
        int hp = t >> 6, h = t & 63;
        ws[WS_WI2T + h * HDIM + hp] = Wi2[hp * HDIM + h];
    }
    if (t < LDIM * HDIM) {                 // Wi3T[h][l] = Wi3[l][h]
        int l = t >> 6, h = t & 63;
        ws[WS_WI3T + h * LDIM + l] = Wi3[l * HDIM + h];
    }
    if (t < HDIM) ws[WS_BI2 + t] = bi2[t];
    if (t < LDIM) {
        ws[WS_BI3 + t] = bi3[t];
        ws[WS_BC  + t] = bcp[t];
        ws[WS_PHW + t] = phw[t];
    }
}

// ---------------- kernel 2: per-row precompute (1 wave per row) ----------------
__global__ __launch_bounds__(64) void precompute(
    const float* __restrict__ state,
    const float* __restrict__ Ws1, const float* __restrict__ bs1,
    const float* __restrict__ Ws2, const float* __restrict__ bs2,
    const float* __restrict__ Ws3, const float* __restrict__ bs3,
    const float* __restrict__ Wi1, const float* __restrict__ bi1,
    const float* __restrict__ Wc,  const float* __restrict__ aggr,
    float* __restrict__ ws) {
    const int i = blockIdx.x;
    const int t = threadIdx.x;
    __shared__ float sh_h[LDIM], sh_dh[LDIM], sh_t1[HDIM], sh_t2[HDIM];

    if (t < LDIM) {
        float v = state[i * (LDIM + 1) + t];
        sh_h[t] = v;
        ws[WS_HT + t * NN + i] = v;
    }
    if (t == LDIM)     ws[WS_PH + i]  = state[i * (LDIM + 1) + LDIM];
    if (t == LDIM + 1) ws[WS_AGG + i] = fast_sigmoid(aggr[i]);
    __syncthreads();

    { // t1 = tanh(Ws1 @ h + bs1)
        float s = bs1[t];
        #pragma unroll
        for (int l = 0; l < LDIM; l++) s += Ws1[t * LDIM + l] * sh_h[l];
        sh_t1[t] = fast_tanh(s);
    }
    __syncthreads();
    { // t2 = tanh(Ws2 @ t1 + bs2)
        float s = bs2[t];
        #pragma unroll
        for (int l = 0; l < HDIM; l++) s += Ws2[t * HDIM + l] * sh_t1[l];
        sh_t2[t] = fast_tanh(s);
    }
    __syncthreads();
    if (t < LDIM) { // self_term = Ws3 @ t2 + bs3
        float s = bs3[t];
        #pragma unroll
        for (int l = 0; l < HDIM; l++) s += Ws3[t * HDIM + l] * sh_t2[l];
        ws[WS_SELF + i * LDIM + t] = s;
        sh_dh[t] = s;
    }
    __syncthreads();
    { // a_i = h@Wi1[:, :L].T + dh@Wi1[:, 2L:3L].T ; b = h@Wi1[:, L:2L].T + dh@Wi1[:, 3L:].T + bi1
        float sa = 0.f, sb = bi1[t];
        #pragma unroll
        for (int l = 0; l < LDIM; l++) {
            float hv = sh_h[l], dv = sh_dh[l];
            sa += Wi1[t * 4 * LDIM + l] * hv;
            sa += Wi1[t * 4 * LDIM + 2 * LDIM + l] * dv;
            sb += Wi1[t * 4 * LDIM + LDIM + l] * hv;
            sb += Wi1[t * 4 * LDIM + 3 * LDIM + l] * dv;
        }
        ws[WS_AA + i * HDIM + t] = sa;
        ws[WS_BT + t * NN + i]   = sb;
    }
    if (t < LDIM) { // ci = h@Wc[:, :L].T ; cj = h@Wc[:, L:].T
        float si = 0.f, sj = 0.f;
        #pragma unroll
        for (int m = 0; m < LDIM; m++) {
            float hv = sh_h[m];
            si += Wc[t * 2 * LDIM + m] * hv;
            sj += Wc[t * 2 * LDIM + LDIM + m] * hv;
        }
        ws[WS_CI + i * LDIM + t]  = si;
        ws[WS_CJT + t * NN + i]   = sj;
    }
}

// ---------------- kernel 3: pairwise core. grid (N, 4) x 256, 1 pair/thread --------
__global__ __launch_bounds__(256) void pair_kernel(float* ws) {
    const int i = blockIdx.x;
    const int j = blockIdx.y * 256 + threadIdx.x;

    const float* aA   = ws + WS_AA + i * HDIM;   // uniform per block
    const float* bT   = ws + WS_BT;
    const float* Wi2T = ws + WS_WI2T;
    const float* Wi3T = ws + WS_WI3T;
    const float* hT   = ws + WS_HT;
    const float* cjT  = ws + WS_CJT;
    const float* ciA  = ws + WS_CI + i * LDIM;

    // stage A: x2acc[h'] = bi2[h'] + sum_h Wi2[h'][h] * tanh(a_i[h] + b_j[h])
    float x2acc[HDIM];
    #pragma unroll
    for (int hp = 0; hp < HDIM; hp++) x2acc[hp] = ws[WS_BI2 + hp];
    #pragma unroll 2
    for (int h = 0; h < HDIM; h++) {
        float x1h = fast_tanh(aA[h] + bT[h * NN + j]);
        #pragma unroll
        for (int hp = 0; hp < HDIM; hp++)
            x2acc[hp] = fmaf(Wi2T[h * HDIM + hp], x1h, x2acc[hp]);
    }

    // stage B: kacc[l] = bi3[l] + sum_h Wi3[l][h] * tanh(x2acc[h])
    float kacc[LDIM];
    #pragma unroll
    for (int l = 0; l < LDIM; l++) kacc[l] = ws[WS_BI3 + l];
    #pragma unroll 2
    for (int h = 0; h < HDIM; h++) {
        float x2h = fast_tanh(x2acc[h]);
        #pragma unroll
        for (int l = 0; l < LDIM; l++)
            kacc[l] = fmaf(Wi3T[h * LDIM + l], x2h, kacc[l]);
    }

    // stage C: distance, phase factor, coherence, combine, reduce over j
    float pd = ws[WS_PH + i] - ws[WS_PH + j];
    float sum2 = 0.f;
    #pragma unroll
    for (int l = 0; l < LDIM; l++) {
        float d = hT[l * NN + i] - hT[l * NN + j];
        sum2 = fmaf(d, d, sum2);
    }
    float dist = sqrtf(sum2) + 1e-6f;
    float dfac = fminf(fast_rcp(dist), 2.0f);
    float fac  = dfac * ws[WS_AGG + i];
    float mask = (j == i) ? 0.0f : 1.0f;

    #pragma unroll
    for (int l = 0; l < LDIM; l++) {
        float diffl = hT[l * NN + i] - hT[l * NN + j];
        float coh = fast_sigmoid(ciA[l] + cjT[l * NN + j] + ws[WS_BC + l]);
        float pf  = __cosf(pd * ws[WS_PHW + l]);
        // inter = dfac*k*agg_i + pf*coh*(-diff)
        float v = (fac * kacc[l] - pf * coh * diffl) * mask;
        // wave(64) reduction, then one atomic per wave per l
        v += __shfl_xor(v, 1);  v += __shfl_xor(v, 2);  v += __shfl_xor(v, 4);
        v += __shfl_xor(v, 8);  v += __shfl_xor(v, 16); v += __shfl_xor(v, 32);
        if ((threadIdx.x & 63) == 0)
            atomicAdd(&ws[WS_ISUM + i * LDIM + l], v);
    }
}

// ---------------- kernel 4: finalize ----------------
__global__ __launch_bounds__(64) void finalize(const float* __restrict__ ws, float* __restrict__ out) {
    int i = blockIdx.x, t = threadIdx.x;
    float isv = 0.f;
    if (t < LDIM) {
        isv = ws[WS_ISUM + i * LDIM + t];
        float dh = 0.5f * ws[WS_SELF + i * LDIM + t] + 0.3f * isv;
        out[i * (LDIM + 1) + t] = dh;
    }
    float a = (t < LDIM) ? fabsf(isv) : 0.f;
    a += __shfl_xor(a, 1);  a += __shfl_xor(a, 2);  a += __shfl_xor(a, 4);
    a += __shfl_xor(a, 8);  a += __shfl_xor(a, 16); a += __shfl_xor(a, 32);
    if (t == 0) out[i * (LDIM + 1) + LDIM] = 0.1f + 0.05f * a;
}

extern "C" void kernel_launch(void* const* d_in, const int* in_sizes, int n_in,
                              void* d_out, int out_size, void* d_ws, size_t ws_size,
                              hipStream_t stream) {
    const float* state   = (const float*)d_in[0];
    const float* Ws1     = (const float*)d_in[1];
    const float* bs1     = (const float*)d_in[2];
    const float* Ws2     = (const float*)d_in[3];
    const float* bs2     = (const float*)d_in[4];
    const float* Ws3     = (const float*)d_in[5];
    const float* bs3     = (const float*)d_in[6];
    const float* Wi1     = (const float*)d_in[7];
    const float* bi1     = (const float*)d_in[8];
    const float* Wi2     = (const float*)d_in[9];
    const float* bi2     = (const float*)d_in[10];
    const float* Wi3     = (const float*)d_in[11];
    const float* bi3     = (const float*)d_in[12];
    const float* phase_w = (const float*)d_in[13];
    const float* Wc      = (const float*)d_in[14];
    const float* bc      = (const float*)d_in[15];
    const float* aggr    = (const float*)d_in[16];

    float* ws = (float*)d_ws;
    float* out = (float*)d_out;

    // zero the fp32 isum accumulators (ws is re-poisoned before every launch)
    hipMemsetAsync(ws + WS_ISUM, 0, NN * LDIM * sizeof(float), stream);

    conv_weights<<<16, 256, 0, stream>>>(Wi2, bi2, Wi3, bi3, bc, phase_w, ws);
    precompute<<<NN, 64, 0, stream>>>(state, Ws1, bs1, Ws2, bs2, Ws3, bs3,
                                      Wi1, bi1, Wc, aggr, ws);
    pair_kernel<<<dim3(NN, 4), 256, 0, stream>>>(ws);
    finalize<<<NN, 64, 0, stream>>>(ws, out);
}

// Round 3
// 190.130 us; speedup vs baseline: 2.0408x; 2.0408x over previous
//
#include <hip/hip_runtime.h>
#include <hip/hip_bf16.h>
#include <math.h>

#define NN 1024
#define LDIM 32
#define HDIM 64

// ---------------- fp32 workspace layout (float offsets) ----------------
#define WS_SELF 0                        // N*L   self_term [i][l]
#define WS_AA   (WS_SELF + NN*LDIM)      // N*H   a_i [i][h]
#define WS_CI   (WS_AA   + NN*HDIM)      // N*L   ci [i][l]
#define WS_AGG  (WS_CI   + NN*LDIM)      // N     sigmoid(aggr)
#define WS_BI2  (WS_AGG  + NN)           // H
#define WS_BI3  (WS_BI2  + HDIM)         // L
#define WS_BCB  (WS_BI3  + LDIM)         // L     bc
#define WS_FEND (WS_BCB  + LDIM)         // 132224 floats (528896 B, 16B-aligned)

// ---------------- bf16(u16) workspace layout (short offsets from wsu) ----
#define U_BJB  0                         // N*H  b_j [j][h] bf16
#define U_HJB  (U_BJB + NN*HDIM)         // N*L  h   [j][l] bf16
#define U_CJB  (U_HJB + NN*LDIM)         // N*L  cj  [j][l] bf16
#define U_PCB  (U_CJB + NN*LDIM)         // N*L  cos(ph_j*phw_l) bf16
#define U_PSB  (U_PCB + NN*LDIM)         // N*L  sin(ph_j*phw_l) bf16
#define U_W2B  (U_PSB + NN*LDIM)         // H*H  Wi2 [n][k] bf16 (row-major, no transpose)
#define U_W3B  (U_W2B + HDIM*HDIM)       // L*H  Wi3 [l][k] bf16

typedef __attribute__((ext_vector_type(8))) short bf16x8;
typedef __attribute__((ext_vector_type(4))) float f32x4;

__device__ __forceinline__ float fast_rcp(float x) { return __builtin_amdgcn_rcpf(x); }
__device__ __forceinline__ float fast_tanh(float x) {
    float e = __expf(2.0f * x);              // saturates cleanly at +-inf
    return 1.0f - 2.0f * fast_rcp(e + 1.0f);
}
__device__ __forceinline__ float fast_sigmoid(float x) {
    return fast_rcp(1.0f + __expf(-x));
}
// bf16 <-> f32 bit tricks (bf16->f32 is exact: bits<<16)
__device__ __forceinline__ float blo(unsigned int u) { union { unsigned int i; float f; } v; v.i = u << 16; return v.f; }
__device__ __forceinline__ float bhi(unsigned int u) { union { unsigned int i; float f; } v; v.i = u & 0xffff0000u; return v.f; }
__device__ __forceinline__ float bf2f(unsigned short u) { union { unsigned int i; float f; } v; v.i = ((unsigned int)u) << 16; return v.f; }
__device__ __forceinline__ unsigned short f2bf(float f) {   // round-to-nearest-even
    union { float f; unsigned int i; } v; v.f = f;
    unsigned int r = v.i + 0x7fffu + ((v.i >> 16) & 1u);
    return (unsigned short)(r >> 16);
}
__device__ __forceinline__ unsigned int pk2(float a, float b) {
    return (unsigned int)f2bf(a) | ((unsigned int)f2bf(b) << 16);
}

// ---------------- kernel 1: convert weights to bf16 / copy biases ----------
__global__ __launch_bounds__(256) void conv_weights(
    const float* __restrict__ Wi2, const float* __restrict__ bi2,
    const float* __restrict__ Wi3, const float* __restrict__ bi3,
    const float* __restrict__ bcp,
    float* __restrict__ ws, unsigned short* __restrict__ wsu) {
    int t = blockIdx.x * 256 + threadIdx.x;
    if (t < HDIM * HDIM) wsu[U_W2B + t] = f2bf(Wi2[t]);
    if (t < LDIM * HDIM) wsu[U_W3B + t] = f2bf(Wi3[t]);
    if (t < HDIM) ws[WS_BI2 + t] = bi2[t];
    if (t < LDIM) { ws[WS_BI3 + t] = bi3[t]; ws[WS_BCB + t] = bcp[t]; }
}

// ---------------- kernel 2: per-row precompute (1 wave per row) ------------
__global__ __launch_bounds__(64) void precompute(
    const float* __restrict__ state,
    const float* __restrict__ Ws1, const float* __restrict__ bs1,
    const float* __restrict__ Ws2, const float* __restrict__ bs2,
    const float* __restrict__ Ws3, const float* __restrict__ bs3,
    const float* __restrict__ Wi1, const float* __restrict__ bi1,
    const float* __restrict__ Wc,  const float* __restrict__ aggr,
    const float* __restrict__ phw,
    float* __restrict__ ws, unsigned short* __restrict__ wsu) {
    const int i = blockIdx.x;
    const int t = threadIdx.x;
    __shared__ float sh_h[LDIM], sh_dh[LDIM], sh_t1[HDIM], sh_t2[HDIM];
    __shared__ float sh_ph;

    if (t < LDIM) {
        float v = state[i * (LDIM + 1) + t];
        sh_h[t] = v;
        wsu[U_HJB + i * LDIM + t] = f2bf(v);
    }
    if (t == LDIM)     sh_ph = state[i * (LDIM + 1) + LDIM];
    if (t == LDIM + 1) ws[WS_AGG + i] = fast_sigmoid(aggr[i]);
    __syncthreads();

    { // t1 = tanh(Ws1 @ h + bs1)
        float s = bs1[t];
        #pragma unroll
        for (int l = 0; l < LDIM; l++) s += Ws1[t * LDIM + l] * sh_h[l];
        sh_t1[t] = fast_tanh(s);
    }
    __syncthreads();
    { // t2 = tanh(Ws2 @ t1 + bs2)
        float s = bs2[t];
        #pragma unroll
        for (int l = 0; l < HDIM; l++) s += Ws2[t * HDIM + l] * sh_t1[l];
        sh_t2[t] = fast_tanh(s);
    }
    __syncthreads();
    if (t < LDIM) { // self_term = Ws3 @ t2 + bs3
        float s = bs3[t];
        #pragma unroll
        for (int l = 0; l < HDIM; l++) s += Ws3[t * HDIM + l] * sh_t2[l];
        ws[WS_SELF + i * LDIM + t] = s;
        sh_dh[t] = s;
    }
    __syncthreads();
    { // a_i (no bias) ; b_j (with bi1)
        float sa = 0.f, sb = bi1[t];
        #pragma unroll
        for (int l = 0; l < LDIM; l++) {
            float hv = sh_h[l], dv = sh_dh[l];
            sa += Wi1[t * 4 * LDIM + l] * hv;
            sa += Wi1[t * 4 * LDIM + 2 * LDIM + l] * dv;
            sb += Wi1[t * 4 * LDIM + LDIM + l] * hv;
            sb += Wi1[t * 4 * LDIM + 3 * LDIM + l] * dv;
        }
        ws[WS_AA + i * HDIM + t]  = sa;
        wsu[U_BJB + i * HDIM + t] = f2bf(sb);
    }
    if (t < LDIM) { // ci, cj, and factored phase tables
        float si = 0.f, sj = 0.f;
        #pragma unroll
        for (int m = 0; m < LDIM; m++) {
            float hv = sh_h[m];
            si += Wc[t * 2 * LDIM + m] * hv;
            sj += Wc[t * 2 * LDIM + LDIM + m] * hv;
        }
        ws[WS_CI + i * LDIM + t]  = si;
        wsu[U_CJB + i * LDIM + t] = f2bf(sj);
        float ang = sh_ph * phw[t];
        wsu[U_PCB + i * LDIM + t] = f2bf(cosf(ang));
        wsu[U_PSB + i * LDIM + t] = f2bf(sinf(ang));
    }
}

// ---------------- kernel 3: MFMA pairwise core (1 block per i) -------------
// 256 threads = 4 waves; each wave owns 16 j-rows per 64-j tile; 16 tiles.
__global__ __launch_bounds__(256, 2) void pair_kernel(
    const float* __restrict__ ws, const unsigned short* __restrict__ wsu,
    float* __restrict__ out) {
    const int i    = blockIdx.x;
    const int tid  = threadIdx.x;
    const int w    = tid >> 6;
    const int lane = tid & 63;
    const int q    = lane >> 4;     // quad
    const int m    = lane & 15;

    // LDS: padded strides (72 shorts / rows) keep fragment reads <=2-way conflicts
    __shared__ unsigned short W2ls[64 * 72];       // Wi2[n][k], row stride 72
    __shared__ unsigned short W3ls[32 * 72];       // Wi3[l][k]
    __shared__ unsigned short x2ls[4 * 16 * 72];   // per-wave 16x64 x2 tile (bf16)
    __shared__ float his[32], cib[32], pic[32], pis[32], bi3ls[32];
    __shared__ float bi2ls[64], aIs[64];
    __shared__ float facs[64];                     // dfac*agg_i per tile-j
    __shared__ float red[4][32];

    // ---- block setup ----
    if (tid < 64) { aIs[tid] = ws[WS_AA + i * 64 + tid]; bi2ls[tid] = ws[WS_BI2 + tid]; }
    if (tid < 32) {
        his[tid]   = bf2f(wsu[U_HJB + i * 32 + tid]);
        cib[tid]   = ws[WS_CI + i * 32 + tid] + ws[WS_BCB + tid];
        pic[tid]   = bf2f(wsu[U_PCB + i * 32 + tid]);
        pis[tid]   = bf2f(wsu[U_PSB + i * 32 + tid]);
        bi3ls[tid] = ws[WS_BI3 + tid];
    }
    { // stage Wi2 (64x64) and Wi3 (32x64) into padded LDS; 16 shorts per thread
        int row = tid >> 2, c = (tid & 3) * 16;
        const uint4* s2 = (const uint4*)(wsu + U_W2B + row * 64 + c);
        uint4 d0 = s2[0], d1 = s2[1];
        uint4* dd = (uint4*)(&W2ls[row * 72 + c]);
        dd[0] = d0; dd[1] = d1;
        if (row < 32) {
            const uint4* s3 = (const uint4*)(wsu + U_W3B + row * 64 + c);
            uint4 e0 = s3[0], e1 = s3[1];
            uint4* d3 = (uint4*)(&W3ls[row * 72 + c]);
            d3[0] = e0; d3[1] = e1;
        }
    }
    const float aggi = ws[WS_AGG + i];
    __syncthreads();

    float accC0 = 0.f, accC1 = 0.f;
    const int jw = w * 16;

    for (int T = 0; T < 16; T++) {
        const int jb = T * 64;

        // 1) cooperative fac[] for this tile's 64 j (4 threads per j, 8 l each)
        {
            int jt = tid >> 2, sub = tid & 3;
            int j = jb + jt;
            union { uint4 u4; unsigned int d[4]; } hv;
            hv.u4 = *(const uint4*)(wsu + U_HJB + j * 32 + sub * 8);
            float s = 0.f;
            const float* hb = &his[sub * 8];
            #pragma unroll
            for (int e = 0; e < 4; e++) {
                float d0 = hb[2 * e]     - blo(hv.d[e]);
                float d1 = hb[2 * e + 1] - bhi(hv.d[e]);
                s = fmaf(d0, d0, s); s = fmaf(d1, d1, s);
            }
            s += __shfl_xor(s, 1); s += __shfl_xor(s, 2);
            if (sub == 0) {
                float dist = sqrtf(s) + 1e-6f;
                facs[jt] = fminf(fast_rcp(dist), 2.0f) * aggi;
            }
        }

        // 2) build x1 A-fragments: x1[j][k] = tanh(a_i[k] + b_j[k]), bf16
        const int jm = jb + jw + m;               // this lane's A-row
        bf16x8 afrag[2];
        #pragma unroll
        for (int s = 0; s < 2; s++) {
            union { uint4 u4; unsigned int d[4]; } bv;
            bv.u4 = *(const uint4*)(wsu + U_BJB + jm * 64 + s * 32 + q * 8);
            const float* ab = &aIs[s * 32 + q * 8];
            union { uint4 u4; bf16x8 v; } pkd;
            #pragma unroll
            for (int e = 0; e < 4; e++) {
                float x0 = fast_tanh(ab[2 * e]     + blo(bv.d[e]));
                float x1 = fast_tanh(ab[2 * e + 1] + bhi(bv.d[e]));
                ((unsigned int*)&pkd.u4)[e] = pk2(x0, x1);
            }
            afrag[s] = pkd.v;
        }

        // 3) stage A MFMAs: X2[j][n] = X1 @ Wi2^T   (B-frag = Wi2[n][k])
        f32x4 accA[4];
        #pragma unroll
        for (int nb = 0; nb < 4; nb++) {
            f32x4 acc = {0.f, 0.f, 0.f, 0.f};
            #pragma unroll
            for (int s = 0; s < 2; s++) {
                bf16x8 bfrag = *(const bf16x8*)(&W2ls[(nb * 16 + m) * 72 + s * 32 + q * 8]);
                acc = __builtin_amdgcn_mfma_f32_16x16x32_bf16(afrag[s], bfrag, acc, 0, 0, 0);
            }
            accA[nb] = acc;
        }
        // epilogue A: x2 = tanh(acc + bi2[n]) -> per-wave LDS tile (bf16)
        {
            unsigned short* xw = &x2ls[w * 16 * 72];
            #pragma unroll
            for (int nb = 0; nb < 4; nb++) {
                float bv = bi2ls[nb * 16 + m];
                #pragma unroll
                for (int r = 0; r < 4; r++) {
                    float x2 = fast_tanh(accA[nb][r] + bv);
                    xw[(q * 4 + r) * 72 + nb * 16 + m] = f2bf(x2);
                }
            }
        }
        __syncthreads();   // x2ls + facs visible

        // 4) stage B MFMAs: K[j][l] = X2t @ Wi3^T   (B-frag = Wi3[l][k])
        f32x4 accB[2];
        {
            bf16x8 x2f[2];
            #pragma unroll
            for (int s = 0; s < 2; s++)
                x2f[s] = *(const bf16x8*)(&x2ls[(w * 16 + m) * 72 + s * 32 + q * 8]);
            #pragma unroll
            for (int lb = 0; lb < 2; lb++) {
                f32x4 acc = {0.f, 0.f, 0.f, 0.f};
                #pragma unroll
                for (int s = 0; s < 2; s++) {
                    bf16x8 w3f = *(const bf16x8*)(&W3ls[(lb * 16 + m) * 72 + s * 32 + q * 8]);
                    acc = __builtin_amdgcn_mfma_f32_16x16x32_bf16(x2f[s], w3f, acc, 0, 0, 0);
                }
                accB[lb] = acc;
            }
        }

        // 5) stage C: combine + accumulate over j (C-frag row = q*4+r, col l = lb*16+m)
        #pragma unroll
        for (int lb = 0; lb < 2; lb++) {
            int l = lb * 16 + m;
            float bi3v = bi3ls[l];
            float hiv = his[l], cibv = cib[l], picv = pic[l], pisv = pis[l];
            float accl = 0.f;
            #pragma unroll
            for (int r = 0; r < 4; r++) {
                int jt = jw + q * 4 + r;
                int j  = jb + jt;
                int off = j * 32 + l;
                float hj  = bf2f(wsu[U_HJB + off]);
                float cj  = bf2f(wsu[U_CJB + off]);
                float pjc = bf2f(wsu[U_PCB + off]);
                float pjs = bf2f(wsu[U_PSB + off]);
                float pf  = picv * pjc + pisv * pjs;        // cos(pd*phw[l]) exactly
                float coh = fast_sigmoid(cibv + cj);
                float kv  = accB[lb][r] + bi3v;
                float v   = facs[jt] * kv - pf * coh * (hiv - hj);
                if (j != i) accl += v;
            }
            if (lb == 0) accC0 += accl; else accC1 += accl;
        }
        __syncthreads();   // before next tile overwrites facs/x2ls
    }

    // ---- final reduction: lanes sharing l are quads (xor 16, 32), then waves via LDS
    accC0 += __shfl_xor(accC0, 16); accC0 += __shfl_xor(accC0, 32);
    accC1 += __shfl_xor(accC1, 16); accC1 += __shfl_xor(accC1, 32);
    if (lane < 16) { red[w][m] = accC0; red[w][16 + m] = accC1; }
    __syncthreads();
    if (tid < 32) {
        float isum = red[0][tid] + red[1][tid] + red[2][tid] + red[3][tid];
        out[i * (LDIM + 1) + tid] = 0.5f * ws[WS_SELF + i * 32 + tid] + 0.3f * isum;
        red[0][tid] = fabsf(isum);
    }
    __syncthreads();
    if (tid == 0) {
        float s = 0.f;
        #pragma unroll
        for (int l = 0; l < 32; l++) s += red[0][l];
        out[i * (LDIM + 1) + LDIM] = 0.1f + 0.05f * s;
    }
}

extern "C" void kernel_launch(void* const* d_in, const int* in_sizes, int n_in,
                              void* d_out, int out_size, void* d_ws, size_t ws_size,
                              hipStream_t stream) {
    const float* state   = (const float*)d_in[0];
    const float* Ws1     = (const float*)d_in[1];
    const float* bs1     = (const float*)d_in[2];
    const float* Ws2     = (const float*)d_in[3];
    const float* bs2     = (const float*)d_in[4];
    const float* Ws3     = (const float*)d_in[5];
    const float* bs3     = (const float*)d_in[6];
    const float* Wi1     = (const float*)d_in[7];
    const float* bi1     = (const float*)d_in[8];
    const float* Wi2     = (const float*)d_in[9];
    const float* bi2     = (const float*)d_in[10];
    const float* Wi3     = (const float*)d_in[11];
    const float* bi3     = (const float*)d_in[12];
    const float* phase_w = (const float*)d_in[13];
    const float* Wc      = (const float*)d_in[14];
    const float* bc      = (const float*)d_in[15];
    const float* aggr    = (const float*)d_in[16];

    float* ws = (float*)d_ws;
    unsigned short* wsu = (unsigned short*)(ws + WS_FEND);
    float* out = (float*)d_out;

    conv_weights<<<16, 256, 0, stream>>>(Wi2, bi2, Wi3, bi3, bc, ws, wsu);
    precompute<<<NN, 64, 0, stream>>>(state, Ws1, bs1, Ws2, bs2, Ws3, bs3,
                                      Wi1, bi1, Wc, aggr, phase_w, ws, wsu);
    pair_kernel<<<NN, 256, 0, stream>>>(ws, wsu, out);
}